// Round 1
// baseline (675.150 us; speedup 1.0000x reference)
//
#include <hip/hip_runtime.h>
#include <cstdint>

#define B_SZ 16
#define T_SZ 2048
#define H_SZ 1024
#define K_SZ 2048              // 2H
#define M_SZ (B_SZ * T_SZ)     // 32768

#define BM 128
#define BN 128
#define BK 64
#define LDK 72                 // padded LDS row stride in halves (+16B)
#define KTILES (K_SZ / BK)     // 32

typedef _Float16 half8_t __attribute__((ext_vector_type(8)));
typedef float float4_t __attribute__((ext_vector_type(4)));

// ---------------------------------------------------------------------------
// Kernel 1: hpart[b][h] = bias[h] + dot(hidden[b, :], W[h, 0:1024])
// One wave per (b,h) pair: lane covers 16 k-elements via 4 float4 loads.
// ---------------------------------------------------------------------------
__global__ __launch_bounds__(256) void hpart_kernel(
    const float* __restrict__ hidden, const float* __restrict__ W,
    const float* __restrict__ bias, float* __restrict__ hpart) {
    int wave = (blockIdx.x * 256 + threadIdx.x) >> 6;  // [0, 16384)
    int lane = threadIdx.x & 63;
    int b = wave >> 10;
    int h = wave & 1023;
    const float* wrow = W + (size_t)h * 3072;
    const float* hrow = hidden + b * H_SZ;
    int k0 = lane * 16;
    float acc = 0.f;
#pragma unroll
    for (int j = 0; j < 4; ++j) {
        float4_t wv = *(const float4_t*)(wrow + k0 + j * 4);
        float4_t hv = *(const float4_t*)(hrow + k0 + j * 4);
        acc += wv[0] * hv[0] + wv[1] * hv[1] + wv[2] * hv[2] + wv[3] * hv[3];
    }
#pragma unroll
    for (int off = 32; off >= 1; off >>= 1) acc += __shfl_xor(acc, off, 64);
    if (lane == 0) hpart[b * H_SZ + h] = acc + bias[h];
}

// ---------------------------------------------------------------------------
// Kernel 2: C = enc @ W2^T (fp16 MFMA, fp32 acc), fused epilogue:
//   partial[slice][m] = sum over this block's 64 n-cols of tanh(C+hpart)*v
// Block tile 128x128, 4 waves of 64x64 (4x4 of 16x16x32 MFMA), BK=64.
// ---------------------------------------------------------------------------
__global__ __launch_bounds__(256, 2) void attn_gemm_kernel(
    const float* __restrict__ enc, const float* __restrict__ W,
    const float* __restrict__ hpart, const float* __restrict__ v,
    float* __restrict__ partial) {
    __shared__ _Float16 Af[BM * LDK];
    __shared__ _Float16 Bf[BN * LDK];
    __shared__ float hp_s[BN];
    __shared__ float v_s[BN];

    const int bidx = blockIdx.x;
    const int blockN = bidx & 7;   // fast-varying -> XCD pins its W2 slice in L2
    const int blockM = bidx >> 3;  // [0, 256)
    const int tid = threadIdx.x;
    const int lane = tid & 63;
    const int w = tid >> 6;
    const int wm = w & 1, wn = w >> 1;
    const int m16 = lane & 15, quad = lane >> 4;

    const int n0 = blockN * BN;
    const int batch = blockM >> 4;  // (blockM*128)/2048

    if (tid < BN) {
        hp_s[tid] = hpart[batch * H_SZ + n0 + tid];
        v_s[tid] = v[n0 + tid];
    }

    float4_t acc[4][4];
#pragma unroll
    for (int i = 0; i < 4; ++i)
#pragma unroll
        for (int j = 0; j < 4; ++j) acc[i][j] = (float4_t){0.f, 0.f, 0.f, 0.f};

    const float* Abase = enc + (size_t)(blockM * BM) * K_SZ;
    const float* Bbase = W + (size_t)n0 * 3072 + H_SZ;  // W2 = W[:, H:3H]

    for (int kt = 0; kt < KTILES; ++kt) {
        __syncthreads();
        // ---- stage A tile (128 x 64 fp32 -> fp16 in LDS) ----
        const float* Asrc0 = Abase + kt * BK;
#pragma unroll
        for (int i = 0; i < 4; ++i) {
            int f8 = i * 256 + tid;  // [0, 1024) groups of 8 halves
            int r = f8 >> 3, c8 = f8 & 7;
            const float* src = Asrc0 + (size_t)r * K_SZ + c8 * 8;
            float4_t lo = *(const float4_t*)(src);
            float4_t hi = *(const float4_t*)(src + 4);
            half8_t hv;
            hv[0] = (_Float16)lo[0]; hv[1] = (_Float16)lo[1];
            hv[2] = (_Float16)lo[2]; hv[3] = (_Float16)lo[3];
            hv[4] = (_Float16)hi[0]; hv[5] = (_Float16)hi[1];
            hv[6] = (_Float16)hi[2]; hv[7] = (_Float16)hi[3];
            *(half8_t*)&Af[r * LDK + c8 * 8] = hv;
        }
        // ---- stage B tile (W2 rows n0..n0+127, stride 3072) ----
        const float* Bsrc0 = Bbase + kt * BK;
#pragma unroll
        for (int i = 0; i < 4; ++i) {
            int f8 = i * 256 + tid;
            int r = f8 >> 3, c8 = f8 & 7;
            const float* src = Bsrc0 + (size_t)r * 3072 + c8 * 8;
            float4_t lo = *(const float4_t*)(src);
            float4_t hi = *(const float4_t*)(src + 4);
            half8_t hv;
            hv[0] = (_Float16)lo[0]; hv[1] = (_Float16)lo[1];
            hv[2] = (_Float16)lo[2]; hv[3] = (_Float16)lo[3];
            hv[4] = (_Float16)hi[0]; hv[5] = (_Float16)hi[1];
            hv[6] = (_Float16)hi[2]; hv[7] = (_Float16)hi[3];
            *(half8_t*)&Bf[r * LDK + c8 * 8] = hv;
        }
        __syncthreads();
        // ---- MFMA over 2 k-steps of 32 ----
#pragma unroll
        for (int ks = 0; ks < 2; ++ks) {
            half8_t afrag[4], bfrag[4];
#pragma unroll
            for (int tm = 0; tm < 4; ++tm)
                afrag[tm] = *(const half8_t*)&Af[(wm * 64 + tm * 16 + m16) * LDK + ks * 32 + quad * 8];
#pragma unroll
            for (int tn = 0; tn < 4; ++tn)
                bfrag[tn] = *(const half8_t*)&Bf[(wn * 64 + tn * 16 + m16) * LDK + ks * 32 + quad * 8];
#pragma unroll
            for (int tm = 0; tm < 4; ++tm)
#pragma unroll
                for (int tn = 0; tn < 4; ++tn)
                    acc[tm][tn] = __builtin_amdgcn_mfma_f32_16x16x32_f16(
                        afrag[tm], bfrag[tn], acc[tm][tn], 0, 0, 0);
        }
    }

    // ---- fused epilogue: tanh(C + hpart) * v, reduce over n ----
    // C/D layout (16x16): n = tn*16 + (lane&15), m = tm*16 + quad*4 + reg
    const int slice = blockN * 2 + wn;  // [0, 16)
#pragma unroll
    for (int tm = 0; tm < 4; ++tm) {
        float s0 = 0.f, s1 = 0.f, s2 = 0.f, s3 = 0.f;
#pragma unroll
        for (int tn = 0; tn < 4; ++tn) {
            int nl = wn * 64 + tn * 16 + m16;
            float hpv = hp_s[nl];
            float vv = v_s[nl];
            s0 += tanhf(acc[tm][tn][0] + hpv) * vv;
            s1 += tanhf(acc[tm][tn][1] + hpv) * vv;
            s2 += tanhf(acc[tm][tn][2] + hpv) * vv;
            s3 += tanhf(acc[tm][tn][3] + hpv) * vv;
        }
#pragma unroll
        for (int off = 1; off < 16; off <<= 1) {
            s0 += __shfl_xor(s0, off, 64);
            s1 += __shfl_xor(s1, off, 64);
            s2 += __shfl_xor(s2, off, 64);
            s3 += __shfl_xor(s3, off, 64);
        }
        if (m16 == 0) {
            int gm = blockM * BM + wm * 64 + tm * 16 + quad * 4;
            float* dst = partial + (size_t)slice * M_SZ + gm;
            dst[0] = s0; dst[1] = s1; dst[2] = s2; dst[3] = s3;
        }
    }
}

// ---------------------------------------------------------------------------
// Kernel 3: per-batch softmax over T=2048; sums the 16 partial slices.
// ---------------------------------------------------------------------------
__global__ __launch_bounds__(256) void softmax_kernel(
    const float* __restrict__ partial, float* __restrict__ out) {
    __shared__ float red[256];
    const int b = blockIdx.x;
    const int tid = threadIdx.x;
    float sc[8];
    float mymax = -1e30f;
#pragma unroll
    for (int i = 0; i < 8; ++i) {
        int t = i * 256 + tid;
        float s = 0.f;
#pragma unroll
        for (int sl = 0; sl < 16; ++sl) s += partial[(size_t)sl * M_SZ + b * T_SZ + t];
        sc[i] = s;
        mymax = fmaxf(mymax, s);
    }
    red[tid] = mymax;
    __syncthreads();
    for (int off = 128; off >= 1; off >>= 1) {
        if (tid < off) red[tid] = fmaxf(red[tid], red[tid + off]);
        __syncthreads();
    }
    float mx = red[0];
    __syncthreads();
    float mysum = 0.f;
#pragma unroll
    for (int i = 0; i < 8; ++i) {
        sc[i] = expf(sc[i] - mx);
        mysum += sc[i];
    }
    red[tid] = mysum;
    __syncthreads();
    for (int off = 128; off >= 1; off >>= 1) {
        if (tid < off) red[tid] += red[tid + off];
        __syncthreads();
    }
    float inv = 1.0f / red[0];
#pragma unroll
    for (int i = 0; i < 8; ++i) out[b * T_SZ + i * 256 + tid] = sc[i] * inv;
}

// ---------------------------------------------------------------------------
extern "C" void kernel_launch(void* const* d_in, const int* in_sizes, int n_in,
                              void* d_out, int out_size, void* d_ws, size_t ws_size,
                              hipStream_t stream) {
    const float* hidden = (const float*)d_in[0];  // (16, 1024)
    const float* enc    = (const float*)d_in[1];  // (16, 2048, 2048)
    const float* W      = (const float*)d_in[2];  // (1024, 3072)
    const float* bias   = (const float*)d_in[3];  // (1024,)
    const float* v      = (const float*)d_in[4];  // (1024,)
    float* out = (float*)d_out;                   // (16, 1, 2048)

    float* hpart = (float*)d_ws;                       // 16*1024 floats (64 KB)
    float* partial = (float*)d_ws + B_SZ * H_SZ;       // 16*32768 floats (2 MB)

    hipLaunchKernelGGL(hpart_kernel, dim3(4096), dim3(256), 0, stream,
                       hidden, W, bias, hpart);
    hipLaunchKernelGGL(attn_gemm_kernel, dim3(2048), dim3(256), 0, stream,
                       enc, W, hpart, v, partial);
    hipLaunchKernelGGL(softmax_kernel, dim3(B_SZ), dim3(256), 0, stream,
                       partial, out);
}

// Round 2
// 571.093 us; speedup vs baseline: 1.1822x; 1.1822x over previous
//
#include <hip/hip_runtime.h>
#include <cstdint>

#define B_SZ 16
#define T_SZ 2048
#define H_SZ 1024
#define K_SZ 2048              // 2H
#define M_SZ (B_SZ * T_SZ)     // 32768

#define BM 128
#define BN 128
#define BK 64
#define LDK 72                 // padded stride for the fallback fp32-staging path
#define KTILES (K_SZ / BK)     // 32

typedef _Float16 half8_t __attribute__((ext_vector_type(8)));
typedef float float4_t __attribute__((ext_vector_type(4)));

__device__ __forceinline__ void glds16(const _Float16* g, _Float16* l) {
    __builtin_amdgcn_global_load_lds(
        (const __attribute__((address_space(1))) void*)g,
        (__attribute__((address_space(3))) void*)l, 16, 0, 0);
}

// ---------------------------------------------------------------------------
// Kernel 0a: convert enc fp32 -> fp16 (64M elements), 8 per thread
// ---------------------------------------------------------------------------
__global__ __launch_bounds__(256) void cvt_enc_kernel(
    const float* __restrict__ src, _Float16* __restrict__ dst) {
    size_t i = ((size_t)blockIdx.x * 256 + threadIdx.x) * 8;
    float4_t a = *(const float4_t*)(src + i);
    float4_t b = *(const float4_t*)(src + i + 4);
    half8_t h;
    h[0] = (_Float16)a[0]; h[1] = (_Float16)a[1];
    h[2] = (_Float16)a[2]; h[3] = (_Float16)a[3];
    h[4] = (_Float16)b[0]; h[5] = (_Float16)b[1];
    h[6] = (_Float16)b[2]; h[7] = (_Float16)b[3];
    *(half8_t*)(dst + i) = h;
}

// ---------------------------------------------------------------------------
// Kernel 0b: W2h[n][k] = (fp16) W[n][1024 + k], n<1024, k<2048
// ---------------------------------------------------------------------------
__global__ __launch_bounds__(256) void cvt_w2_kernel(
    const float* __restrict__ W, _Float16* __restrict__ dst) {
    int idx8 = blockIdx.x * 256 + threadIdx.x;  // [0, 262144)
    int n = idx8 >> 8, k8 = (idx8 & 255) * 8;
    const float* src = W + (size_t)n * 3072 + H_SZ + k8;
    float4_t a = *(const float4_t*)(src);
    float4_t b = *(const float4_t*)(src + 4);
    half8_t h;
    h[0] = (_Float16)a[0]; h[1] = (_Float16)a[1];
    h[2] = (_Float16)a[2]; h[3] = (_Float16)a[3];
    h[4] = (_Float16)b[0]; h[5] = (_Float16)b[1];
    h[6] = (_Float16)b[2]; h[7] = (_Float16)b[3];
    *(half8_t*)(dst + (size_t)n * K_SZ + k8) = h;
}

// ---------------------------------------------------------------------------
// Kernel 1: hpart[b][h] = bias[h] + dot(hidden[b, :], W[h, 0:1024])
// ---------------------------------------------------------------------------
__global__ __launch_bounds__(256) void hpart_kernel(
    const float* __restrict__ hidden, const float* __restrict__ W,
    const float* __restrict__ bias, float* __restrict__ hpart) {
    int wave = (blockIdx.x * 256 + threadIdx.x) >> 6;  // [0, 16384)
    int lane = threadIdx.x & 63;
    int b = wave >> 10;
    int h = wave & 1023;
    const float* wrow = W + (size_t)h * 3072;
    const float* hrow = hidden + b * H_SZ;
    int k0 = lane * 16;
    float acc = 0.f;
#pragma unroll
    for (int j = 0; j < 4; ++j) {
        float4_t wv = *(const float4_t*)(wrow + k0 + j * 4);
        float4_t hv = *(const float4_t*)(hrow + k0 + j * 4);
        acc += wv[0] * hv[0] + wv[1] * hv[1] + wv[2] * hv[2] + wv[3] * hv[3];
    }
#pragma unroll
    for (int off = 32; off >= 1; off >>= 1) acc += __shfl_xor(acc, off, 64);
    if (lane == 0) hpart[b * H_SZ + h] = acc + bias[h];
}

// ---------------------------------------------------------------------------
// Kernel 2 (fast path): fp16 GEMM with global_load_lds staging (m97 structure)
//   C = enc16 @ W2h^T, epilogue: partial[slice][m] = sum_n tanh(C+hpart)*v
// ---------------------------------------------------------------------------
__global__ __launch_bounds__(256, 2) void attn_gemm16_kernel(
    const _Float16* __restrict__ A, const _Float16* __restrict__ Bm,
    const float* __restrict__ hpart, const float* __restrict__ v,
    float* __restrict__ partial) {
    __shared__ _Float16 Af[BM * BK];  // unpadded: global_load_lds needs lane-contiguous
    __shared__ _Float16 Bf[BN * BK];
    __shared__ float hp_s[BN];
    __shared__ float v_s[BN];

    const int bidx = blockIdx.x;
    const int blockN = bidx & 7;
    const int blockM = bidx >> 3;
    const int tid = threadIdx.x;
    const int lane = tid & 63;
    const int w = tid >> 6;
    const int wm = w & 1, wn = w >> 1;
    const int m16 = lane & 15, quad = lane >> 4;

    const int n0 = blockN * BN;
    const int batch = blockM >> 4;

    if (tid < BN) {
        hp_s[tid] = hpart[batch * H_SZ + n0 + tid];
        v_s[tid] = v[n0 + tid];
    }

    float4_t acc[4][4];
#pragma unroll
    for (int i = 0; i < 4; ++i)
#pragma unroll
        for (int j = 0; j < 4; ++j) acc[i][j] = (float4_t){0.f, 0.f, 0.f, 0.f};

    const _Float16* Abase = A + (size_t)(blockM * BM) * K_SZ;
    const _Float16* Bbase = Bm + (size_t)n0 * K_SZ;

    const int r_s = tid >> 3;        // row this thread stages (iter 0)
    const int c8_s = (tid & 7) * 8;  // col offset in halves

    for (int kt = 0; kt < KTILES; ++kt) {
        __syncthreads();
        const _Float16* As = Abase + kt * BK;
        const _Float16* Bs = Bbase + kt * BK;
#pragma unroll
        for (int i = 0; i < 4; ++i) {
            int idx16 = i * 256 + tid;
            glds16(As + (size_t)(r_s + i * 32) * K_SZ + c8_s, &Af[idx16 * 8]);
        }
#pragma unroll
        for (int i = 0; i < 4; ++i) {
            int idx16 = i * 256 + tid;
            glds16(Bs + (size_t)(r_s + i * 32) * K_SZ + c8_s, &Bf[idx16 * 8]);
        }
        __syncthreads();
#pragma unroll
        for (int ks = 0; ks < 2; ++ks) {
            half8_t afrag[4], bfrag[4];
#pragma unroll
            for (int tm = 0; tm < 4; ++tm)
                afrag[tm] = *(const half8_t*)&Af[(wm * 64 + tm * 16 + m16) * BK + ks * 32 + quad * 8];
#pragma unroll
            for (int tn = 0; tn < 4; ++tn)
                bfrag[tn] = *(const half8_t*)&Bf[(wn * 64 + tn * 16 + m16) * BK + ks * 32 + quad * 8];
#pragma unroll
            for (int tm = 0; tm < 4; ++tm)
#pragma unroll
                for (int tn = 0; tn < 4; ++tn)
                    acc[tm][tn] = __builtin_amdgcn_mfma_f32_16x16x32_f16(
                        afrag[tm], bfrag[tn], acc[tm][tn], 0, 0, 0);
        }
    }

    const int slice = blockN * 2 + wn;
#pragma unroll
    for (int tm = 0; tm < 4; ++tm) {
        float s0 = 0.f, s1 = 0.f, s2 = 0.f, s3 = 0.f;
#pragma unroll
        for (int tn = 0; tn < 4; ++tn) {
            int nl = wn * 64 + tn * 16 + m16;
            float hpv = hp_s[nl];
            float vv = v_s[nl];
            s0 += tanhf(acc[tm][tn][0] + hpv) * vv;
            s1 += tanhf(acc[tm][tn][1] + hpv) * vv;
            s2 += tanhf(acc[tm][tn][2] + hpv) * vv;
            s3 += tanhf(acc[tm][tn][3] + hpv) * vv;
        }
#pragma unroll
        for (int off = 1; off < 16; off <<= 1) {
            s0 += __shfl_xor(s0, off, 64);
            s1 += __shfl_xor(s1, off, 64);
            s2 += __shfl_xor(s2, off, 64);
            s3 += __shfl_xor(s3, off, 64);
        }
        if (m16 == 0) {
            int gm = blockM * BM + wm * 64 + tm * 16 + quad * 4;
            float* dst = partial + (size_t)slice * M_SZ + gm;
            dst[0] = s0; dst[1] = s1; dst[2] = s2; dst[3] = s3;
        }
    }
}

// ---------------------------------------------------------------------------
// Kernel 2 (fallback, round-1): fp32 loads with in-flight cvt (if ws too small)
// ---------------------------------------------------------------------------
__global__ __launch_bounds__(256, 2) void attn_gemm_kernel(
    const float* __restrict__ enc, const float* __restrict__ W,
    const float* __restrict__ hpart, const float* __restrict__ v,
    float* __restrict__ partial) {
    __shared__ _Float16 Af[BM * LDK];
    __shared__ _Float16 Bf[BN * LDK];
    __shared__ float hp_s[BN];
    __shared__ float v_s[BN];

    const int bidx = blockIdx.x;
    const int blockN = bidx & 7;
    const int blockM = bidx >> 3;
    const int tid = threadIdx.x;
    const int lane = tid & 63;
    const int w = tid >> 6;
    const int wm = w & 1, wn = w >> 1;
    const int m16 = lane & 15, quad = lane >> 4;

    const int n0 = blockN * BN;
    const int batch = blockM >> 4;

    if (tid < BN) {
        hp_s[tid] = hpart[batch * H_SZ + n0 + tid];
        v_s[tid] = v[n0 + tid];
    }

    float4_t acc[4][4];
#pragma unroll
    for (int i = 0; i < 4; ++i)
#pragma unroll
        for (int j = 0; j < 4; ++j) acc[i][j] = (float4_t){0.f, 0.f, 0.f, 0.f};

    const float* Abase = enc + (size_t)(blockM * BM) * K_SZ;
    const float* Bbase = W + (size_t)n0 * 3072 + H_SZ;

    for (int kt = 0; kt < KTILES; ++kt) {
        __syncthreads();
        const float* Asrc0 = Abase + kt * BK;
#pragma unroll
        for (int i = 0; i < 4; ++i) {
            int f8 = i * 256 + tid;
            int r = f8 >> 3, c8 = f8 & 7;
            const float* src = Asrc0 + (size_t)r * K_SZ + c8 * 8;
            float4_t lo = *(const float4_t*)(src);
            float4_t hi = *(const float4_t*)(src + 4);
            half8_t hv;
            hv[0] = (_Float16)lo[0]; hv[1] = (_Float16)lo[1];
            hv[2] = (_Float16)lo[2]; hv[3] = (_Float16)lo[3];
            hv[4] = (_Float16)hi[0]; hv[5] = (_Float16)hi[1];
            hv[6] = (_Float16)hi[2]; hv[7] = (_Float16)hi[3];
            *(half8_t*)&Af[r * LDK + c8 * 8] = hv;
        }
        const float* Bsrc0 = Bbase + kt * BK;
#pragma unroll
        for (int i = 0; i < 4; ++i) {
            int f8 = i * 256 + tid;
            int r = f8 >> 3, c8 = f8 & 7;
            const float* src = Bsrc0 + (size_t)r * 3072 + c8 * 8;
            float4_t lo = *(const float4_t*)(src);
            float4_t hi = *(const float4_t*)(src + 4);
            half8_t hv;
            hv[0] = (_Float16)lo[0]; hv[1] = (_Float16)lo[1];
            hv[2] = (_Float16)lo[2]; hv[3] = (_Float16)lo[3];
            hv[4] = (_Float16)hi[0]; hv[5] = (_Float16)hi[1];
            hv[6] = (_Float16)hi[2]; hv[7] = (_Float16)hi[3];
            *(half8_t*)&Bf[r * LDK + c8 * 8] = hv;
        }
        __syncthreads();
#pragma unroll
        for (int ks = 0; ks < 2; ++ks) {
            half8_t afrag[4], bfrag[4];
#pragma unroll
            for (int tm = 0; tm < 4; ++tm)
                afrag[tm] = *(const half8_t*)&Af[(wm * 64 + tm * 16 + m16) * LDK + ks * 32 + quad * 8];
#pragma unroll
            for (int tn = 0; tn < 4; ++tn)
                bfrag[tn] = *(const half8_t*)&Bf[(wn * 64 + tn * 16 + m16) * LDK + ks * 32 + quad * 8];
#pragma unroll
            for (int tm = 0; tm < 4; ++tm)
#pragma unroll
                for (int tn = 0; tn < 4; ++tn)
                    acc[tm][tn] = __builtin_amdgcn_mfma_f32_16x16x32_f16(
                        afrag[tm], bfrag[tn], acc[tm][tn], 0, 0, 0);
        }
    }

    const int slice = blockN * 2 + wn;
#pragma unroll
    for (int tm = 0; tm < 4; ++tm) {
        float s0 = 0.f, s1 = 0.f, s2 = 0.f, s3 = 0.f;
#pragma unroll
        for (int tn = 0; tn < 4; ++tn) {
            int nl = wn * 64 + tn * 16 + m16;
            float hpv = hp_s[nl];
            float vv = v_s[nl];
            s0 += tanhf(acc[tm][tn][0] + hpv) * vv;
            s1 += tanhf(acc[tm][tn][1] + hpv) * vv;
            s2 += tanhf(acc[tm][tn][2] + hpv) * vv;
            s3 += tanhf(acc[tm][tn][3] + hpv) * vv;
        }
#pragma unroll
        for (int off = 1; off < 16; off <<= 1) {
            s0 += __shfl_xor(s0, off, 64);
            s1 += __shfl_xor(s1, off, 64);
            s2 += __shfl_xor(s2, off, 64);
            s3 += __shfl_xor(s3, off, 64);
        }
        if (m16 == 0) {
            int gm = blockM * BM + wm * 64 + tm * 16 + quad * 4;
            float* dst = partial + (size_t)slice * M_SZ + gm;
            dst[0] = s0; dst[1] = s1; dst[2] = s2; dst[3] = s3;
        }
    }
}

// ---------------------------------------------------------------------------
// Kernel 3: per-batch softmax over T=2048; sums the 16 partial slices.
// ---------------------------------------------------------------------------
__global__ __launch_bounds__(256) void softmax_kernel(
    const float* __restrict__ partial, float* __restrict__ out) {
    __shared__ float red[256];
    const int b = blockIdx.x;
    const int tid = threadIdx.x;
    float sc[8];
    float mymax = -1e30f;
#pragma unroll
    for (int i = 0; i < 8; ++i) {
        int t = i * 256 + tid;
        float s = 0.f;
#pragma unroll
        for (int sl = 0; sl < 16; ++sl) s += partial[(size_t)sl * M_SZ + b * T_SZ + t];
        sc[i] = s;
        mymax = fmaxf(mymax, s);
    }
    red[tid] = mymax;
    __syncthreads();
    for (int off = 128; off >= 1; off >>= 1) {
        if (tid < off) red[tid] = fmaxf(red[tid], red[tid + off]);
        __syncthreads();
    }
    float mx = red[0];
    __syncthreads();
    float mysum = 0.f;
#pragma unroll
    for (int i = 0; i < 8; ++i) {
        sc[i] = expf(sc[i] - mx);
        mysum += sc[i];
    }
    red[tid] = mysum;
    __syncthreads();
    for (int off = 128; off >= 1; off >>= 1) {
        if (tid < off) red[tid] += red[tid + off];
        __syncthreads();
    }
    float inv = 1.0f / red[0];
#pragma unroll
    for (int i = 0; i < 8; ++i) out[b * T_SZ + i * 256 + tid] = sc[i] * inv;
}

// ---------------------------------------------------------------------------
extern "C" void kernel_launch(void* const* d_in, const int* in_sizes, int n_in,
                              void* d_out, int out_size, void* d_ws, size_t ws_size,
                              hipStream_t stream) {
    const float* hidden = (const float*)d_in[0];  // (16, 1024)
    const float* enc    = (const float*)d_in[1];  // (16, 2048, 2048)
    const float* W      = (const float*)d_in[2];  // (1024, 3072)
    const float* bias   = (const float*)d_in[3];  // (1024,)
    const float* v      = (const float*)d_in[4];  // (1024,)
    float* out = (float*)d_out;                   // (16, 1, 2048)

    // ws layout: hpart (64 KB) | partial (2 MB) | W2h (4 MB) | enc16 (128 MB)
    float* hpart   = (float*)d_ws;
    float* partial = hpart + B_SZ * H_SZ;
    _Float16* w2h  = (_Float16*)(partial + 16 * M_SZ);
    _Float16* e16  = w2h + (size_t)H_SZ * K_SZ;
    const size_t need = (size_t)((char*)(e16 + (size_t)M_SZ * K_SZ) - (char*)d_ws);

    hipLaunchKernelGGL(hpart_kernel, dim3(4096), dim3(256), 0, stream,
                       hidden, W, bias, hpart);
    if (ws_size >= need) {
        hipLaunchKernelGGL(cvt_enc_kernel, dim3(32768), dim3(256), 0, stream, enc, e16);
        hipLaunchKernelGGL(cvt_w2_kernel, dim3(1024), dim3(256), 0, stream, W, w2h);
        hipLaunchKernelGGL(attn_gemm16_kernel, dim3(2048), dim3(256), 0, stream,
                           e16, w2h, hpart, v, partial);
    } else {
        hipLaunchKernelGGL(attn_gemm_kernel, dim3(2048), dim3(256), 0, stream,
                           enc, W, hpart, v, partial);
    }
    hipLaunchKernelGGL(softmax_kernel, dim3(B_SZ), dim3(256), 0, stream,
                       partial, out);
}

// Round 3
// 566.491 us; speedup vs baseline: 1.1918x; 1.0081x over previous
//
#include <hip/hip_runtime.h>
#include <cstdint>

#define B_SZ 16
#define T_SZ 2048
#define H_SZ 1024
#define K_SZ 2048              // 2H
#define M_SZ (B_SZ * T_SZ)     // 32768

#define BM 128
#define BN 128
#define BK 64
#define LDK 72                 // padded stride for the fallback fp32-staging path
#define KTILES (K_SZ / BK)     // 32

typedef _Float16 half8_t __attribute__((ext_vector_type(8)));
typedef float float4_t __attribute__((ext_vector_type(4)));

__device__ __forceinline__ void glds16(const _Float16* g, _Float16* l) {
    __builtin_amdgcn_global_load_lds(
        (const __attribute__((address_space(1))) void*)g,
        (__attribute__((address_space(3))) void*)l, 16, 0, 0);
}

// ---------------------------------------------------------------------------
// Kernel 0a: convert enc fp32 -> fp16 (64M elements), 8 per thread
// ---------------------------------------------------------------------------
__global__ __launch_bounds__(256) void cvt_enc_kernel(
    const float* __restrict__ src, _Float16* __restrict__ dst) {
    size_t i = ((size_t)blockIdx.x * 256 + threadIdx.x) * 8;
    float4_t a = *(const float4_t*)(src + i);
    float4_t b = *(const float4_t*)(src + i + 4);
    half8_t h;
    h[0] = (_Float16)a[0]; h[1] = (_Float16)a[1];
    h[2] = (_Float16)a[2]; h[3] = (_Float16)a[3];
    h[4] = (_Float16)b[0]; h[5] = (_Float16)b[1];
    h[6] = (_Float16)b[2]; h[7] = (_Float16)b[3];
    *(half8_t*)(dst + i) = h;
}

// ---------------------------------------------------------------------------
// Kernel 0b: W2h[n][k] = (fp16) W[n][1024 + k], n<1024, k<2048
// ---------------------------------------------------------------------------
__global__ __launch_bounds__(256) void cvt_w2_kernel(
    const float* __restrict__ W, _Float16* __restrict__ dst) {
    int idx8 = blockIdx.x * 256 + threadIdx.x;  // [0, 262144)
    int n = idx8 >> 8, k8 = (idx8 & 255) * 8;
    const float* src = W + (size_t)n * 3072 + H_SZ + k8;
    float4_t a = *(const float4_t*)(src);
    float4_t b = *(const float4_t*)(src + 4);
    half8_t h;
    h[0] = (_Float16)a[0]; h[1] = (_Float16)a[1];
    h[2] = (_Float16)a[2]; h[3] = (_Float16)a[3];
    h[4] = (_Float16)b[0]; h[5] = (_Float16)b[1];
    h[6] = (_Float16)b[2]; h[7] = (_Float16)b[3];
    *(half8_t*)(dst + (size_t)n * K_SZ + k8) = h;
}

// ---------------------------------------------------------------------------
// Kernel 1: hpart[b][h] = bias[h] + dot(hidden[b, :], W[h, 0:1024])
// ---------------------------------------------------------------------------
__global__ __launch_bounds__(256) void hpart_kernel(
    const float* __restrict__ hidden, const float* __restrict__ W,
    const float* __restrict__ bias, float* __restrict__ hpart) {
    int wave = (blockIdx.x * 256 + threadIdx.x) >> 6;  // [0, 16384)
    int lane = threadIdx.x & 63;
    int b = wave >> 10;
    int h = wave & 1023;
    const float* wrow = W + (size_t)h * 3072;
    const float* hrow = hidden + b * H_SZ;
    int k0 = lane * 16;
    float acc = 0.f;
#pragma unroll
    for (int j = 0; j < 4; ++j) {
        float4_t wv = *(const float4_t*)(wrow + k0 + j * 4);
        float4_t hv = *(const float4_t*)(hrow + k0 + j * 4);
        acc += wv[0] * hv[0] + wv[1] * hv[1] + wv[2] * hv[2] + wv[3] * hv[3];
    }
#pragma unroll
    for (int off = 32; off >= 1; off >>= 1) acc += __shfl_xor(acc, off, 64);
    if (lane == 0) hpart[b * H_SZ + h] = acc + bias[h];
}

// ---------------------------------------------------------------------------
// Kernel 2 (fast path): fp16 GEMM, global_load_lds staging + XOR-swizzled LDS
//   LDS slot for (row r, 16B-colgroup j) is at colgroup (j ^ (r&7)):
//   kills the 16-way same-bank-group collision of the unpadded layout while
//   keeping glds16 destinations lane-sequential (padding would break them).
// ---------------------------------------------------------------------------
__global__ __launch_bounds__(256, 4) void attn_gemm16_kernel(
    const _Float16* __restrict__ A, const _Float16* __restrict__ Bm,
    const float* __restrict__ hpart, const float* __restrict__ v,
    float* __restrict__ partial) {
    __shared__ _Float16 Af[BM * BK];
    __shared__ _Float16 Bf[BN * BK];
    __shared__ float hp_s[BN];
    __shared__ float v_s[BN];

    const int bidx = blockIdx.x;
    const int blockN = bidx & 7;
    const int blockM = bidx >> 3;
    const int tid = threadIdx.x;
    const int lane = tid & 63;
    const int w = tid >> 6;
    const int wm = w & 1, wn = w >> 1;
    const int m16 = lane & 15, quad = lane >> 4;
    const int sw = m16 & 7;  // row-dependent swizzle key for fragment reads

    const int n0 = blockN * BN;
    const int batch = blockM >> 4;

    if (tid < BN) {
        hp_s[tid] = hpart[batch * H_SZ + n0 + tid];
        v_s[tid] = v[n0 + tid];
    }

    float4_t acc[4][4];
#pragma unroll
    for (int i = 0; i < 4; ++i)
#pragma unroll
        for (int j = 0; j < 4; ++j) acc[i][j] = (float4_t){0.f, 0.f, 0.f, 0.f};

    const _Float16* Abase = A + (size_t)(blockM * BM) * K_SZ;
    const _Float16* Bbase = Bm + (size_t)n0 * K_SZ;

    // staging: thread stages rows r_s + 32*i; its global 16B-colgroup is the
    // swizzle-inverse of its fixed LDS slot (tid&7): j = (tid&7) ^ (r&7)
    const int r_s = tid >> 3;
    const int jcol = (((tid & 7) ^ ((tid >> 3) & 7))) * 8;  // halves

    for (int kt = 0; kt < KTILES; ++kt) {
        __syncthreads();
        const _Float16* As = Abase + kt * BK + jcol;
        const _Float16* Bs = Bbase + kt * BK + jcol;
#pragma unroll
        for (int i = 0; i < 4; ++i) {
            int slot = i * 256 + tid;
            glds16(As + (size_t)(r_s + i * 32) * K_SZ, &Af[slot * 8]);
        }
#pragma unroll
        for (int i = 0; i < 4; ++i) {
            int slot = i * 256 + tid;
            glds16(Bs + (size_t)(r_s + i * 32) * K_SZ, &Bf[slot * 8]);
        }
        __syncthreads();
#pragma unroll
        for (int ks = 0; ks < 2; ++ks) {
            half8_t afrag[4], bfrag[4];
#pragma unroll
            for (int tm = 0; tm < 4; ++tm) {
                int r = wm * 64 + tm * 16 + m16;           // r&7 == sw
                int p = ((ks * 4 + quad) ^ sw) * 8;
                afrag[tm] = *(const half8_t*)&Af[r * BK + p];
            }
#pragma unroll
            for (int tn = 0; tn < 4; ++tn) {
                int r = wn * 64 + tn * 16 + m16;
                int p = ((ks * 4 + quad) ^ sw) * 8;
                bfrag[tn] = *(const half8_t*)&Bf[r * BK + p];
            }
#pragma unroll
            for (int tm = 0; tm < 4; ++tm)
#pragma unroll
                for (int tn = 0; tn < 4; ++tn)
                    acc[tm][tn] = __builtin_amdgcn_mfma_f32_16x16x32_f16(
                        afrag[tm], bfrag[tn], acc[tm][tn], 0, 0, 0);
        }
    }

    const int slice = blockN * 2 + wn;
#pragma unroll
    for (int tm = 0; tm < 4; ++tm) {
        float s0 = 0.f, s1 = 0.f, s2 = 0.f, s3 = 0.f;
#pragma unroll
        for (int tn = 0; tn < 4; ++tn) {
            int nl = wn * 64 + tn * 16 + m16;
            float hpv = hp_s[nl];
            float vv = v_s[nl];
            s0 += tanhf(acc[tm][tn][0] + hpv) * vv;
            s1 += tanhf(acc[tm][tn][1] + hpv) * vv;
            s2 += tanhf(acc[tm][tn][2] + hpv) * vv;
            s3 += tanhf(acc[tm][tn][3] + hpv) * vv;
        }
#pragma unroll
        for (int off = 1; off < 16; off <<= 1) {
            s0 += __shfl_xor(s0, off, 64);
            s1 += __shfl_xor(s1, off, 64);
            s2 += __shfl_xor(s2, off, 64);
            s3 += __shfl_xor(s3, off, 64);
        }
        if (m16 == 0) {
            int gm = blockM * BM + wm * 64 + tm * 16 + quad * 4;
            float* dst = partial + (size_t)slice * M_SZ + gm;
            dst[0] = s0; dst[1] = s1; dst[2] = s2; dst[3] = s3;
        }
    }
}

// ---------------------------------------------------------------------------
// Kernel 2 (fallback, round-1): fp32 loads with in-flight cvt (if ws too small)
// ---------------------------------------------------------------------------
__global__ __launch_bounds__(256, 2) void attn_gemm_kernel(
    const float* __restrict__ enc, const float* __restrict__ W,
    const float* __restrict__ hpart, const float* __restrict__ v,
    float* __restrict__ partial) {
    __shared__ _Float16 Af[BM * LDK];
    __shared__ _Float16 Bf[BN * LDK];
    __shared__ float hp_s[BN];
    __shared__ float v_s[BN];

    const int bidx = blockIdx.x;
    const int blockN = bidx & 7;
    const int blockM = bidx >> 3;
    const int tid = threadIdx.x;
    const int lane = tid & 63;
    const int w = tid >> 6;
    const int wm = w & 1, wn = w >> 1;
    const int m16 = lane & 15, quad = lane >> 4;

    const int n0 = blockN * BN;
    const int batch = blockM >> 4;

    if (tid < BN) {
        hp_s[tid] = hpart[batch * H_SZ + n0 + tid];
        v_s[tid] = v[n0 + tid];
    }

    float4_t acc[4][4];
#pragma unroll
    for (int i = 0; i < 4; ++i)
#pragma unroll
        for (int j = 0; j < 4; ++j) acc[i][j] = (float4_t){0.f, 0.f, 0.f, 0.f};

    const float* Abase = enc + (size_t)(blockM * BM) * K_SZ;
    const float* Bbase = W + (size_t)n0 * 3072 + H_SZ;

    for (int kt = 0; kt < KTILES; ++kt) {
        __syncthreads();
        const float* Asrc0 = Abase + kt * BK;
#pragma unroll
        for (int i = 0; i < 4; ++i) {
            int f8 = i * 256 + tid;
            int r = f8 >> 3, c8 = f8 & 7;
            const float* src = Asrc0 + (size_t)r * K_SZ + c8 * 8;
            float4_t lo = *(const float4_t*)(src);
            float4_t hi = *(const float4_t*)(src + 4);
            half8_t hv;
            hv[0] = (_Float16)lo[0]; hv[1] = (_Float16)lo[1];
            hv[2] = (_Float16)lo[2]; hv[3] = (_Float16)lo[3];
            hv[4] = (_Float16)hi[0]; hv[5] = (_Float16)hi[1];
            hv[6] = (_Float16)hi[2]; hv[7] = (_Float16)hi[3];
            *(half8_t*)&Af[r * LDK + c8 * 8] = hv;
        }
        const float* Bsrc0 = Bbase + kt * BK;
#pragma unroll
        for (int i = 0; i < 4; ++i) {
            int f8 = i * 256 + tid;
            int r = f8 >> 3, c8 = f8 & 7;
            const float* src = Bsrc0 + (size_t)r * 3072 + c8 * 8;
            float4_t lo = *(const float4_t*)(src);
            float4_t hi = *(const float4_t*)(src + 4);
            half8_t hv;
            hv[0] = (_Float16)lo[0]; hv[1] = (_Float16)lo[1];
            hv[2] = (_Float16)lo[2]; hv[3] = (_Float16)lo[3];
            hv[4] = (_Float16)hi[0]; hv[5] = (_Float16)hi[1];
            hv[6] = (_Float16)hi[2]; hv[7] = (_Float16)hi[3];
            *(half8_t*)&Bf[r * LDK + c8 * 8] = hv;
        }
        __syncthreads();
#pragma unroll
        for (int ks = 0; ks < 2; ++ks) {
            half8_t afrag[4], bfrag[4];
#pragma unroll
            for (int tm = 0; tm < 4; ++tm)
                afrag[tm] = *(const half8_t*)&Af[(wm * 64 + tm * 16 + m16) * LDK + ks * 32 + quad * 8];
#pragma unroll
            for (int tn = 0; tn < 4; ++tn)
                bfrag[tn] = *(const half8_t*)&Bf[(wn * 64 + tn * 16 + m16) * LDK + ks * 32 + quad * 8];
#pragma unroll
            for (int tm = 0; tm < 4; ++tm)
#pragma unroll
                for (int tn = 0; tn < 4; ++tn)
                    acc[tm][tn] = __builtin_amdgcn_mfma_f32_16x16x32_f16(
                        afrag[tm], bfrag[tn], acc[tm][tn], 0, 0, 0);
        }
    }

    const int slice = blockN * 2 + wn;
#pragma unroll
    for (int tm = 0; tm < 4; ++tm) {
        float s0 = 0.f, s1 = 0.f, s2 = 0.f, s3 = 0.f;
#pragma unroll
        for (int tn = 0; tn < 4; ++tn) {
            int nl = wn * 64 + tn * 16 + m16;
            float hpv = hp_s[nl];
            float vv = v_s[nl];
            s0 += tanhf(acc[tm][tn][0] + hpv) * vv;
            s1 += tanhf(acc[tm][tn][1] + hpv) * vv;
            s2 += tanhf(acc[tm][tn][2] + hpv) * vv;
            s3 += tanhf(acc[tm][tn][3] + hpv) * vv;
        }
#pragma unroll
        for (int off = 1; off < 16; off <<= 1) {
            s0 += __shfl_xor(s0, off, 64);
            s1 += __shfl_xor(s1, off, 64);
            s2 += __shfl_xor(s2, off, 64);
            s3 += __shfl_xor(s3, off, 64);
        }
        if (m16 == 0) {
            int gm = blockM * BM + wm * 64 + tm * 16 + quad * 4;
            float* dst = partial + (size_t)slice * M_SZ + gm;
            dst[0] = s0; dst[1] = s1; dst[2] = s2; dst[3] = s3;
        }
    }
}

// ---------------------------------------------------------------------------
// Kernel 3: per-batch softmax over T=2048; sums the 16 partial slices.
// ---------------------------------------------------------------------------
__global__ __launch_bounds__(256) void softmax_kernel(
    const float* __restrict__ partial, float* __restrict__ out) {
    __shared__ float red[256];
    const int b = blockIdx.x;
    const int tid = threadIdx.x;
    float sc[8];
    float mymax = -1e30f;
#pragma unroll
    for (int i = 0; i < 8; ++i) {
        int t = i * 256 + tid;
        float s = 0.f;
#pragma unroll
        for (int sl = 0; sl < 16; ++sl) s += partial[(size_t)sl * M_SZ + b * T_SZ + t];
        sc[i] = s;
        mymax = fmaxf(mymax, s);
    }
    red[tid] = mymax;
    __syncthreads();
    for (int off = 128; off >= 1; off >>= 1) {
        if (tid < off) red[tid] = fmaxf(red[tid], red[tid + off]);
        __syncthreads();
    }
    float mx = red[0];
    __syncthreads();
    float mysum = 0.f;
#pragma unroll
    for (int i = 0; i < 8; ++i) {
        sc[i] = expf(sc[i] - mx);
        mysum += sc[i];
    }
    red[tid] = mysum;
    __syncthreads();
    for (int off = 128; off >= 1; off >>= 1) {
        if (tid < off) red[tid] += red[tid + off];
        __syncthreads();
    }
    float inv = 1.0f / red[0];
#pragma unroll
    for (int i = 0; i < 8; ++i) out[b * T_SZ + i * 256 + tid] = sc[i] * inv;
}

// ---------------------------------------------------------------------------
extern "C" void kernel_launch(void* const* d_in, const int* in_sizes, int n_in,
                              void* d_out, int out_size, void* d_ws, size_t ws_size,
                              hipStream_t stream) {
    const float* hidden = (const float*)d_in[0];  // (16, 1024)
    const float* enc    = (const float*)d_in[1];  // (16, 2048, 2048)
    const float* W      = (const float*)d_in[2];  // (1024, 3072)
    const float* bias   = (const float*)d_in[3];  // (1024,)
    const float* v      = (const float*)d_in[4];  // (1024,)
    float* out = (float*)d_out;                   // (16, 1, 2048)

    // ws layout: hpart (64 KB) | partial (2 MB) | W2h (4 MB) | enc16 (128 MB)
    float* hpart   = (float*)d_ws;
    float* partial = hpart + B_SZ * H_SZ;
    _Float16* w2h  = (_Float16*)(partial + 16 * M_SZ);
    _Float16* e16  = w2h + (size_t)H_SZ * K_SZ;
    const size_t need = (size_t)((char*)(e16 + (size_t)M_SZ * K_SZ) - (char*)d_ws);

    hipLaunchKernelGGL(hpart_kernel, dim3(4096), dim3(256), 0, stream,
                       hidden, W, bias, hpart);
    if (ws_size >= need) {
        hipLaunchKernelGGL(cvt_enc_kernel, dim3(32768), dim3(256), 0, stream, enc, e16);
        hipLaunchKernelGGL(cvt_w2_kernel, dim3(1024), dim3(256), 0, stream, W, w2h);
        hipLaunchKernelGGL(attn_gemm16_kernel, dim3(2048), dim3(256), 0, stream,
                           e16, w2h, hpart, v, partial);
    } else {
        hipLaunchKernelGGL(attn_gemm_kernel, dim3(2048), dim3(256), 0, stream,
                           enc, W, hpart, v, partial);
    }
    hipLaunchKernelGGL(softmax_kernel, dim3(B_SZ), dim3(256), 0, stream,
                       partial, out);
}

// Round 4
// 557.957 us; speedup vs baseline: 1.2100x; 1.0153x over previous
//
#include <hip/hip_runtime.h>
#include <cstdint>

#define B_SZ 16
#define T_SZ 2048
#define H_SZ 1024
#define K_SZ 2048              // 2H
#define M_SZ (B_SZ * T_SZ)     // 32768

#define BM 128
#define BN 128
#define BK 64
#define LDK 72                 // padded stride for the fallback fp32-staging path
#define KTILES (K_SZ / BK)     // 32

typedef _Float16 half8_t __attribute__((ext_vector_type(8)));
typedef float float4_t __attribute__((ext_vector_type(4)));

__device__ __forceinline__ void glds16(const _Float16* g, _Float16* l) {
    __builtin_amdgcn_global_load_lds(
        (const __attribute__((address_space(1))) void*)g,
        (__attribute__((address_space(3))) void*)l, 16, 0, 0);
}

// ---------------------------------------------------------------------------
// Kernel 0a: convert enc fp32 -> fp16 (64M elements), 8 per thread
// ---------------------------------------------------------------------------
__global__ __launch_bounds__(256) void cvt_enc_kernel(
    const float* __restrict__ src, _Float16* __restrict__ dst) {
    size_t i = ((size_t)blockIdx.x * 256 + threadIdx.x) * 8;
    float4_t a = *(const float4_t*)(src + i);
    float4_t b = *(const float4_t*)(src + i + 4);
    half8_t h;
    h[0] = (_Float16)a[0]; h[1] = (_Float16)a[1];
    h[2] = (_Float16)a[2]; h[3] = (_Float16)a[3];
    h[4] = (_Float16)b[0]; h[5] = (_Float16)b[1];
    h[6] = (_Float16)b[2]; h[7] = (_Float16)b[3];
    *(half8_t*)(dst + i) = h;
}

// ---------------------------------------------------------------------------
// Kernel 0b: W2 -> fp16, packed FRAGMENT-MAJOR for direct global->VGPR frags:
//   Bp[((nblk*64 + kblk)*64 + quad*16 + m16)*8 + j] = W[n][1024+k]
//   where n = nblk*16 + m16, k = kblk*32 + quad*8 + j.
//   A wave's B-frag load (fixed nblk,kblk; lane = quad*16+m16) is then one
//   fully-coalesced 1 KB global_load_dwordx4 — no LDS round-trip for B.
// ---------------------------------------------------------------------------
__global__ __launch_bounds__(256) void cvt_w2_kernel(
    const float* __restrict__ W, _Float16* __restrict__ dst) {
    int idx8 = blockIdx.x * 256 + threadIdx.x;  // [0, 262144)
    int n = idx8 >> 8, k = (idx8 & 255) * 8;
    const float* src = W + (size_t)n * 3072 + H_SZ + k;
    float4_t a = *(const float4_t*)(src);
    float4_t b = *(const float4_t*)(src + 4);
    half8_t h;
    h[0] = (_Float16)a[0]; h[1] = (_Float16)a[1];
    h[2] = (_Float16)a[2]; h[3] = (_Float16)a[3];
    h[4] = (_Float16)b[0]; h[5] = (_Float16)b[1];
    h[6] = (_Float16)b[2]; h[7] = (_Float16)b[3];
    int nblk = n >> 4, m16 = n & 15;
    int kblk = k >> 5, quad = (k >> 3) & 3;
    size_t di = (((size_t)nblk * 64 + kblk) * 64 + quad * 16 + m16) * 8;
    *(half8_t*)(dst + di) = h;
}

// ---------------------------------------------------------------------------
// Kernel 1: hpart[b][h] = bias[h] + dot(hidden[b, :], W[h, 0:1024])
// ---------------------------------------------------------------------------
__global__ __launch_bounds__(256) void hpart_kernel(
    const float* __restrict__ hidden, const float* __restrict__ W,
    const float* __restrict__ bias, float* __restrict__ hpart) {
    int wave = (blockIdx.x * 256 + threadIdx.x) >> 6;  // [0, 16384)
    int lane = threadIdx.x & 63;
    int b = wave >> 10;
    int h = wave & 1023;
    const float* wrow = W + (size_t)h * 3072;
    const float* hrow = hidden + b * H_SZ;
    int k0 = lane * 16;
    float acc = 0.f;
#pragma unroll
    for (int j = 0; j < 4; ++j) {
        float4_t wv = *(const float4_t*)(wrow + k0 + j * 4);
        float4_t hv = *(const float4_t*)(hrow + k0 + j * 4);
        acc += wv[0] * hv[0] + wv[1] * hv[1] + wv[2] * hv[2] + wv[3] * hv[3];
    }
#pragma unroll
    for (int off = 32; off >= 1; off >>= 1) acc += __shfl_xor(acc, off, 64);
    if (lane == 0) hpart[b * H_SZ + h] = acc + bias[h];
}

// ---------------------------------------------------------------------------
// Kernel 2 (fast path): fp16 GEMM. A: global_load_lds + XOR-swizzled LDS.
// B: direct global->VGPR fragment loads from the packed Bp (L2-hot, 512 KB
// per XCD) — decoupled from the A-staging barrier, no LDS traffic.
// ---------------------------------------------------------------------------
__global__ __launch_bounds__(256, 4) void attn_gemm16_kernel(
    const _Float16* __restrict__ A, const _Float16* __restrict__ Bp,
    const float* __restrict__ hpart, const float* __restrict__ v,
    float* __restrict__ partial) {
    __shared__ _Float16 Af[BM * BK];
    __shared__ float hp_s[BN];
    __shared__ float v_s[BN];

    const int bidx = blockIdx.x;
    const int blockN = bidx & 7;
    const int blockM = bidx >> 3;
    const int tid = threadIdx.x;
    const int lane = tid & 63;
    const int w = tid >> 6;
    const int wm = w & 1, wn = w >> 1;
    const int m16 = lane & 15, quad = lane >> 4;
    const int sw = m16 & 7;  // row-dependent swizzle key for A fragment reads

    const int n0 = blockN * BN;
    const int batch = blockM >> 4;

    if (tid < BN) {
        hp_s[tid] = hpart[batch * H_SZ + n0 + tid];
        v_s[tid] = v[n0 + tid];
    }

    float4_t acc[4][4];
#pragma unroll
    for (int i = 0; i < 4; ++i)
#pragma unroll
        for (int j = 0; j < 4; ++j) acc[i][j] = (float4_t){0.f, 0.f, 0.f, 0.f};

    const _Float16* Abase = A + (size_t)(blockM * BM) * K_SZ;
    // B frag base for this wave: nblk0 = blockN*8 + wn*4
    const _Float16* Bfr = Bp + (((size_t)(blockN * 8 + wn * 4) * 64) * 64 + lane) * 8;
    // offset(tn, kblk) = tn*(64*64*8) + kblk*(64*8)

    const int r_s = tid >> 3;
    const int jcol = (((tid & 7) ^ ((tid >> 3) & 7))) * 8;  // swizzled colgroup

    for (int kt = 0; kt < KTILES; ++kt) {
        __syncthreads();
        const _Float16* As = Abase + kt * BK + jcol;
#pragma unroll
        for (int i = 0; i < 4; ++i) {
            int slot = i * 256 + tid;
            glds16(As + (size_t)(r_s + i * 32) * K_SZ, &Af[slot * 8]);
        }
        // B fragments for this ktile: coalesced global (L2-hot), no LDS
        half8_t bfrag[2][4];
#pragma unroll
        for (int ks = 0; ks < 2; ++ks)
#pragma unroll
            for (int tn = 0; tn < 4; ++tn)
                bfrag[ks][tn] = *(const half8_t*)(
                    Bfr + (size_t)tn * (64 * 64 * 8) + (size_t)(kt * 2 + ks) * (64 * 8));
        __syncthreads();
#pragma unroll
        for (int ks = 0; ks < 2; ++ks) {
            half8_t afrag[4];
#pragma unroll
            for (int tm = 0; tm < 4; ++tm) {
                int r = wm * 64 + tm * 16 + m16;  // r&7 == sw
                int p = ((ks * 4 + quad) ^ sw) * 8;
                afrag[tm] = *(const half8_t*)&Af[r * BK + p];
            }
#pragma unroll
            for (int tm = 0; tm < 4; ++tm)
#pragma unroll
                for (int tn = 0; tn < 4; ++tn)
                    acc[tm][tn] = __builtin_amdgcn_mfma_f32_16x16x32_f16(
                        afrag[tm], bfrag[ks][tn], acc[tm][tn], 0, 0, 0);
        }
    }

    const int slice = blockN * 2 + wn;
#pragma unroll
    for (int tm = 0; tm < 4; ++tm) {
        float s0 = 0.f, s1 = 0.f, s2 = 0.f, s3 = 0.f;
#pragma unroll
        for (int tn = 0; tn < 4; ++tn) {
            int nl = wn * 64 + tn * 16 + m16;
            float hpv = hp_s[nl];
            float vv = v_s[nl];
            s0 += tanhf(acc[tm][tn][0] + hpv) * vv;
            s1 += tanhf(acc[tm][tn][1] + hpv) * vv;
            s2 += tanhf(acc[tm][tn][2] + hpv) * vv;
            s3 += tanhf(acc[tm][tn][3] + hpv) * vv;
        }
#pragma unroll
        for (int off = 1; off < 16; off <<= 1) {
            s0 += __shfl_xor(s0, off, 64);
            s1 += __shfl_xor(s1, off, 64);
            s2 += __shfl_xor(s2, off, 64);
            s3 += __shfl_xor(s3, off, 64);
        }
        if (m16 == 0) {
            int gm = blockM * BM + wm * 64 + tm * 16 + quad * 4;
            float* dst = partial + (size_t)slice * M_SZ + gm;
            dst[0] = s0; dst[1] = s1; dst[2] = s2; dst[3] = s3;
        }
    }
}

// ---------------------------------------------------------------------------
// Kernel 2 (fallback, round-1): fp32 loads with in-flight cvt (if ws too small)
// ---------------------------------------------------------------------------
__global__ __launch_bounds__(256, 2) void attn_gemm_kernel(
    const float* __restrict__ enc, const float* __restrict__ W,
    const float* __restrict__ hpart, const float* __restrict__ v,
    float* __restrict__ partial) {
    __shared__ _Float16 Af[BM * LDK];
    __shared__ _Float16 Bf[BN * LDK];
    __shared__ float hp_s[BN];
    __shared__ float v_s[BN];

    const int bidx = blockIdx.x;
    const int blockN = bidx & 7;
    const int blockM = bidx >> 3;
    const int tid = threadIdx.x;
    const int lane = tid & 63;
    const int w = tid >> 6;
    const int wm = w & 1, wn = w >> 1;
    const int m16 = lane & 15, quad = lane >> 4;

    const int n0 = blockN * BN;
    const int batch = blockM >> 4;

    if (tid < BN) {
        hp_s[tid] = hpart[batch * H_SZ + n0 + tid];
        v_s[tid] = v[n0 + tid];
    }

    float4_t acc[4][4];
#pragma unroll
    for (int i = 0; i < 4; ++i)
#pragma unroll
        for (int j = 0; j < 4; ++j) acc[i][j] = (float4_t){0.f, 0.f, 0.f, 0.f};

    const float* Abase = enc + (size_t)(blockM * BM) * K_SZ;
    const float* Bbase = W + (size_t)n0 * 3072 + H_SZ;

    for (int kt = 0; kt < KTILES; ++kt) {
        __syncthreads();
        const float* Asrc0 = Abase + kt * BK;
#pragma unroll
        for (int i = 0; i < 4; ++i) {
            int f8 = i * 256 + tid;
            int r = f8 >> 3, c8 = f8 & 7;
            const float* src = Asrc0 + (size_t)r * K_SZ + c8 * 8;
            float4_t lo = *(const float4_t*)(src);
            float4_t hi = *(const float4_t*)(src + 4);
            half8_t hv;
            hv[0] = (_Float16)lo[0]; hv[1] = (_Float16)lo[1];
            hv[2] = (_Float16)lo[2]; hv[3] = (_Float16)lo[3];
            hv[4] = (_Float16)hi[0]; hv[5] = (_Float16)hi[1];
            hv[6] = (_Float16)hi[2]; hv[7] = (_Float16)hi[3];
            *(half8_t*)&Af[r * LDK + c8 * 8] = hv;
        }
        const float* Bsrc0 = Bbase + kt * BK;
#pragma unroll
        for (int i = 0; i < 4; ++i) {
            int f8 = i * 256 + tid;
            int r = f8 >> 3, c8 = f8 & 7;
            const float* src = Bsrc0 + (size_t)r * 3072 + c8 * 8;
            float4_t lo = *(const float4_t*)(src);
            float4_t hi = *(const float4_t*)(src + 4);
            half8_t hv;
            hv[0] = (_Float16)lo[0]; hv[1] = (_Float16)lo[1];
            hv[2] = (_Float16)lo[2]; hv[3] = (_Float16)lo[3];
            hv[4] = (_Float16)hi[0]; hv[5] = (_Float16)hi[1];
            hv[6] = (_Float16)hi[2]; hv[7] = (_Float16)hi[3];
            *(half8_t*)&Bf[r * LDK + c8 * 8] = hv;
        }
        __syncthreads();
#pragma unroll
        for (int ks = 0; ks < 2; ++ks) {
            half8_t afrag[4], bfrag[4];
#pragma unroll
            for (int tm = 0; tm < 4; ++tm)
                afrag[tm] = *(const half8_t*)&Af[(wm * 64 + tm * 16 + m16) * LDK + ks * 32 + quad * 8];
#pragma unroll
            for (int tn = 0; tn < 4; ++tn)
                bfrag[tn] = *(const half8_t*)&Bf[(wn * 64 + tn * 16 + m16) * LDK + ks * 32 + quad * 8];
#pragma unroll
            for (int tm = 0; tm < 4; ++tm)
#pragma unroll
                for (int tn = 0; tn < 4; ++tn)
                    acc[tm][tn] = __builtin_amdgcn_mfma_f32_16x16x32_f16(
                        afrag[tm], bfrag[tn], acc[tm][tn], 0, 0, 0);
        }
    }

    const int slice = blockN * 2 + wn;
#pragma unroll
    for (int tm = 0; tm < 4; ++tm) {
        float s0 = 0.f, s1 = 0.f, s2 = 0.f, s3 = 0.f;
#pragma unroll
        for (int tn = 0; tn < 4; ++tn) {
            int nl = wn * 64 + tn * 16 + m16;
            float hpv = hp_s[nl];
            float vv = v_s[nl];
            s0 += tanhf(acc[tm][tn][0] + hpv) * vv;
            s1 += tanhf(acc[tm][tn][1] + hpv) * vv;
            s2 += tanhf(acc[tm][tn][2] + hpv) * vv;
            s3 += tanhf(acc[tm][tn][3] + hpv) * vv;
        }
#pragma unroll
        for (int off = 1; off < 16; off <<= 1) {
            s0 += __shfl_xor(s0, off, 64);
            s1 += __shfl_xor(s1, off, 64);
            s2 += __shfl_xor(s2, off, 64);
            s3 += __shfl_xor(s3, off, 64);
        }
        if (m16 == 0) {
            int gm = blockM * BM + wm * 64 + tm * 16 + quad * 4;
            float* dst = partial + (size_t)slice * M_SZ + gm;
            dst[0] = s0; dst[1] = s1; dst[2] = s2; dst[3] = s3;
        }
    }
}

// ---------------------------------------------------------------------------
// Kernel 3: per-batch softmax over T=2048; sums the 16 partial slices.
// ---------------------------------------------------------------------------
__global__ __launch_bounds__(256) void softmax_kernel(
    const float* __restrict__ partial, float* __restrict__ out) {
    __shared__ float red[256];
    const int b = blockIdx.x;
    const int tid = threadIdx.x;
    float sc[8];
    float mymax = -1e30f;
#pragma unroll
    for (int i = 0; i < 8; ++i) {
        int t = i * 256 + tid;
        float s = 0.f;
#pragma unroll
        for (int sl = 0; sl < 16; ++sl) s += partial[(size_t)sl * M_SZ + b * T_SZ + t];
        sc[i] = s;
        mymax = fmaxf(mymax, s);
    }
    red[tid] = mymax;
    __syncthreads();
    for (int off = 128; off >= 1; off >>= 1) {
        if (tid < off) red[tid] = fmaxf(red[tid], red[tid + off]);
        __syncthreads();
    }
    float mx = red[0];
    __syncthreads();
    float mysum = 0.f;
#pragma unroll
    for (int i = 0; i < 8; ++i) {
        sc[i] = expf(sc[i] - mx);
        mysum += sc[i];
    }
    red[tid] = mysum;
    __syncthreads();
    for (int off = 128; off >= 1; off >>= 1) {
        if (tid < off) red[tid] += red[tid + off];
        __syncthreads();
    }
    float inv = 1.0f / red[0];
#pragma unroll
    for (int i = 0; i < 8; ++i) out[b * T_SZ + i * 256 + tid] = sc[i] * inv;
}

// ---------------------------------------------------------------------------
extern "C" void kernel_launch(void* const* d_in, const int* in_sizes, int n_in,
                              void* d_out, int out_size, void* d_ws, size_t ws_size,
                              hipStream_t stream) {
    const float* hidden = (const float*)d_in[0];  // (16, 1024)
    const float* enc    = (const float*)d_in[1];  // (16, 2048, 2048)
    const float* W      = (const float*)d_in[2];  // (1024, 3072)
    const float* bias   = (const float*)d_in[3];  // (1024,)
    const float* v      = (const float*)d_in[4];  // (1024,)
    float* out = (float*)d_out;                   // (16, 1, 2048)

    // ws layout: hpart (64 KB) | partial (2 MB) | W2h packed (4 MB) | enc16 (128 MB)
    float* hpart   = (float*)d_ws;
    float* partial = hpart + B_SZ * H_SZ;
    _Float16* w2h  = (_Float16*)(partial + 16 * M_SZ);
    _Float16* e16  = w2h + (size_t)H_SZ * K_SZ;
    const size_t need = (size_t)((char*)(e16 + (size_t)M_SZ * K_SZ) - (char*)d_ws);

    hipLaunchKernelGGL(hpart_kernel, dim3(4096), dim3(256), 0, stream,
                       hidden, W, bias, hpart);
    if (ws_size >= need) {
        hipLaunchKernelGGL(cvt_enc_kernel, dim3(32768), dim3(256), 0, stream, enc, e16);
        hipLaunchKernelGGL(cvt_w2_kernel, dim3(1024), dim3(256), 0, stream, W, w2h);
        hipLaunchKernelGGL(attn_gemm16_kernel, dim3(2048), dim3(256), 0, stream,
                           e16, w2h, hpart, v, partial);
    } else {
        hipLaunchKernelGGL(attn_gemm_kernel, dim3(2048), dim3(256), 0, stream,
                           enc, W, hpart, v, partial);
    }
    hipLaunchKernelGGL(softmax_kernel, dim3(B_SZ), dim3(256), 0, stream,
                       partial, out);
}